// Round 4
// baseline (469.151 us; speedup 1.0000x reference)
//
#include <hip/hip_runtime.h>

// PartialProductAccumulator: 54-step ripple add with dropped carry-out
// == sum of 54 partial products mod 2^108.
// K1: per-bit-column popcount (exact in fp32, max 54), streamed from HBM.
//     1 float4 column/thread, 1728 blocks (27 waves/CU), depth-4 software
//     pipeline (4 nontemporal loads in flight per wave).
// K2: in-place per-row 108-bit carry propagation, one thread per row.

#define N_PP   54
#define BITS   108
#define BATCH  16384
#define ROW_F4 (BITS / 4)                    // 27 float4 per row
#define PLANE_F4 ((size_t)BATCH * ROW_F4)    // 442368 float4 per p-plane

typedef float vf4 __attribute__((ext_vector_type(4)));

// ---------------- K1: column counts ----------------
__global__ __launch_bounds__(256)
void count_kernel(const vf4* __restrict__ pps, vf4* __restrict__ cnt) {
    const size_t i0 = (size_t)blockIdx.x * 256 + threadIdx.x;
    const vf4* p = pps + i0;

    vf4 acc = (vf4)(0.f);

    // depth-4 pipeline: 4 loads in flight at all times
    vf4 v0 = __builtin_nontemporal_load(p + 0 * PLANE_F4);
    vf4 v1 = __builtin_nontemporal_load(p + 1 * PLANE_F4);
    vf4 v2 = __builtin_nontemporal_load(p + 2 * PLANE_F4);
    vf4 v3 = __builtin_nontemporal_load(p + 3 * PLANE_F4);

    // planes 4..51 in groups of 4 (12 iterations)
    for (int q = 4; q + 4 <= N_PP - 2; q += 4) {
        const vf4* pq = p + (size_t)q * PLANE_F4;
        vf4 n0 = __builtin_nontemporal_load(pq + 0 * PLANE_F4);
        vf4 n1 = __builtin_nontemporal_load(pq + 1 * PLANE_F4);
        vf4 n2 = __builtin_nontemporal_load(pq + 2 * PLANE_F4);
        vf4 n3 = __builtin_nontemporal_load(pq + 3 * PLANE_F4);
        acc += v0; acc += v1; acc += v2; acc += v3;
        v0 = n0; v1 = n1; v2 = n2; v3 = n3;
    }

    // epilogue: planes 52,53 plus the last pipelined group
    vf4 e0 = __builtin_nontemporal_load(p + (size_t)(N_PP - 2) * PLANE_F4);
    vf4 e1 = __builtin_nontemporal_load(p + (size_t)(N_PP - 1) * PLANE_F4);
    acc += v0; acc += v1; acc += v2; acc += v3;
    acc += e0; acc += e1;

    cnt[i0] = acc;   // regular store: stays cache-warm for K2
}

// ---------------- K2: carry propagation ----------------
// One thread per batch row. Row counts -> registers (27 independent float4
// loads), serial carry chain, write back in place (rows disjoint across
// threads; K1->K2 stream-ordered).
__global__ __launch_bounds__(64)
void carry_kernel(vf4* __restrict__ buf) {
    const int row = blockIdx.x * 64 + threadIdx.x;
    vf4* rp = buf + (size_t)row * ROW_F4;

    float r[BITS];
#pragma unroll
    for (int j = 0; j < ROW_F4; ++j) {
        reinterpret_cast<vf4*>(r)[j] = rp[j];
    }

    int c = 0;
#pragma unroll
    for (int i = 0; i < BITS; ++i) {
        const int t = (int)r[i] + c;
        r[i] = (float)(t & 1);
        c = t >> 1;                          // carry out of bit 107 dropped
    }

#pragma unroll
    for (int j = 0; j < ROW_F4; ++j) {
        rp[j] = reinterpret_cast<vf4*>(r)[j];
    }
}

extern "C" void kernel_launch(void* const* d_in, const int* in_sizes, int n_in,
                              void* d_out, int out_size, void* d_ws, size_t ws_size,
                              hipStream_t stream) {
    const vf4* pps = (const vf4*)d_in[0];
    vf4* out = (vf4*)d_out;

    count_kernel<<<(int)(PLANE_F4 / 256), 256, 0, stream>>>(pps, out);
    carry_kernel<<<BATCH / 64, 64, 0, stream>>>(out);
}